// Round 2
// baseline (2123.565 us; speedup 1.0000x reference)
//
#include <hip/hip_runtime.h>
#include <stdint.h>

// LTC encoder: B=256, T=1024, F=64, H=128, 2 layers, LN after each cell. All f32.
// One workgroup per batch row; full T-scan inside the WG (rows independent).
// Weights register-stationary (160 fp32/thread); activations broadcast via LDS.

#define B_ 256
#define T_ 1024
#define F_ 64
#define H_ 128
#define EPS_ 1e-5f
#define CH_ 64               // x chunk length (steps) staged in LDS (16 KB)
#define NT_ 512              // threads per block (8 waves)

__device__ __forceinline__ float tanh_fast(float a) {
  float aa = fabsf(a);
  float e  = __expf(2.f * aa);          // inf for large aa -> th -> 1
  float th = 1.f - 2.f / (e + 1.f);
  return copysignf(th, a);
}

__device__ __forceinline__ float softplus_fast(float x) {
  return (x > 20.f) ? x : __logf(1.f + __expf(x));
}

__global__ void __launch_bounds__(NT_, 2) ltc_scan(
    const float* __restrict__ x,
    const float* __restrict__ Wh0, const float* __restrict__ bh0,
    const float* __restrict__ Wx0, const float* __restrict__ bx0,
    const float* __restrict__ Wt0, const float* __restrict__ bt0,
    const float* __restrict__ tau0, const float* __restrict__ g0,
    const float* __restrict__ be0,
    const float* __restrict__ Wh1, const float* __restrict__ bh1,
    const float* __restrict__ Wx1, const float* __restrict__ bx1,
    const float* __restrict__ Wt1, const float* __restrict__ bt1,
    const float* __restrict__ tau1, const float* __restrict__ g1,
    const float* __restrict__ be1,
    float* __restrict__ out)
{
  __shared__ __align__(16) float4 xcu[CH_ * F_ / 4];   // 1024 float4 = 16 KB
  __shared__ __align__(16) float  hs0[H_];
  __shared__ __align__(16) float  hs1[H_];
  __shared__ float pA0[4 * H_], pT0[4 * H_], pA1[4 * H_], pT1[4 * H_];
  __shared__ float2 wsum0[8], wsum1[8];

  const int tid  = threadIdx.x;
  const int j    = tid & 127;      // output index
  const int q    = tid >> 7;       // K-quarter 0..3
  const int lane = tid & 63;
  const int wid  = tid >> 6;       // wave 0..7
  const int b    = blockIdx.x;

  // ---------- register-stationary weights (f32, float4 loads) ----------
  float wh0[32], wx0[16], wt0[16], wh1[32], wx1[32], wt1[32];
  {
    const float4* p = (const float4*)(Wh0 + j * 128 + q * 32);
    #pragma unroll
    for (int i = 0; i < 8; ++i) ((float4*)wh0)[i] = p[i];
    p = (const float4*)(Wx0 + j * 64 + q * 16);
    #pragma unroll
    for (int i = 0; i < 4; ++i) ((float4*)wx0)[i] = p[i];
    p = (const float4*)(Wt0 + j * 64 + q * 16);
    #pragma unroll
    for (int i = 0; i < 4; ++i) ((float4*)wt0)[i] = p[i];
    p = (const float4*)(Wh1 + j * 128 + q * 32);
    #pragma unroll
    for (int i = 0; i < 8; ++i) ((float4*)wh1)[i] = p[i];
    p = (const float4*)(Wx1 + j * 128 + q * 32);
    #pragma unroll
    for (int i = 0; i < 8; ++i) ((float4*)wx1)[i] = p[i];
    p = (const float4*)(Wt1 + j * 128 + q * 32);
    #pragma unroll
    for (int i = 0; i < 8; ++i) ((float4*)wt1)[i] = p[i];
  }
  const float bhx0  = bh0[j] + bx0[j];
  const float bt0r  = bt0[j];
  const float tau0r = tau0[j];
  const float g0r   = g0[j];
  const float be0r  = be0[j];
  const float bhx1  = bh1[j] + bx1[j];
  const float bt1r  = bt1[j];
  const float tau1r = tau1[j];
  const float g1r   = g1[j];
  const float be1r  = be1[j];

  // ---------- init state ----------
  if (tid < H_) { hs0[tid] = 0.f; hs1[tid] = 0.f; }

  // ---------- x row staging: chunk 0 now, chunk 1 prefetched to regs ----------
  const float4* xsrc = (const float4*)(x + (size_t)b * (T_ * F_));  // 16384 float4 / row
  float4 r0 = xsrc[tid];
  float4 r1 = xsrc[tid + 512];
  xcu[tid] = r0; xcu[tid + 512] = r1;
  r0 = xsrc[1024 + tid];
  r1 = xsrc[1536 + tid];
  __syncthreads();

  float out_hn1 = 0.f;

  for (int t = 0; t < T_; ++t) {
    // ================= layer 0: partial dots =================
    float pa = 0.f, pt = 0.f;
    {
      const float4* hq = (const float4*)(hs0 + q * 32);
      #pragma unroll
      for (int i4 = 0; i4 < 8; ++i4) {
        float4 hv = hq[i4];                       // broadcast ds_read_b128
        pa = fmaf(wh0[4 * i4 + 0], hv.x, pa);
        pa = fmaf(wh0[4 * i4 + 1], hv.y, pa);
        pa = fmaf(wh0[4 * i4 + 2], hv.z, pa);
        pa = fmaf(wh0[4 * i4 + 3], hv.w, pa);
      }
      const float4* xp = xcu + (t & (CH_ - 1)) * (F_ / 4) + q * 4;
      float xv[16];
      #pragma unroll
      for (int i = 0; i < 4; ++i) ((float4*)xv)[i] = xp[i];
      #pragma unroll
      for (int i = 0; i < 16; ++i) {
        pa = fmaf(wx0[i], xv[i], pa);
        pt = fmaf(wt0[i], xv[i], pt);
      }
    }
    pA0[q * H_ + j] = pa;
    pT0[q * H_ + j] = pt;
    __syncthreads();                                             // B1

    // ---- combine + cell + LN stats (redundant across q-groups) ----
    float a  = pA0[j] + pA0[H_ + j] + pA0[2 * H_ + j] + pA0[3 * H_ + j] + bhx0;
    float ta = pT0[j] + pT0[H_ + j] + pT0[2 * H_ + j] + pT0[3 * H_ + j] + bt0r;
    float f   = tanh_fast(a);
    float tau = tau0r + softplus_fast(ta);
    float hold = hs0[j];
    float hc   = fmaf(f - hold, __builtin_amdgcn_rcpf(tau), hold);
    float s = hc, s2 = hc * hc;
    #pragma unroll
    for (int off = 32; off >= 1; off >>= 1) {
      s  += __shfl_xor(s, off);
      s2 += __shfl_xor(s2, off);
    }
    if (lane == 0) wsum0[wid] = make_float2(s, s2);
    __syncthreads();                                             // B2
    {
      float2 sA = wsum0[0], sB = wsum0[1];                       // waves 0,1 cover j 0..127
      float mu   = (sA.x + sB.x) * (1.f / 128.f);
      float var  = (sA.y + sB.y) * (1.f / 128.f) - mu * mu;
      float rstd = rsqrtf(var + EPS_);
      float hn0  = (hc - mu) * rstd * g0r + be0r;
      if (q == 0) hs0[j] = hn0;
    }
    __syncthreads();                                             // B3

    // ================= layer 1: partial dots =================
    float pa1 = 0.f, pt1 = 0.f;
    {
      const float4* hqa = (const float4*)(hs1 + q * 32);         // Wh1 . h1
      const float4* hqb = (const float4*)(hs0 + q * 32);         // Wx1/Wt1 . h0_new
      #pragma unroll
      for (int i4 = 0; i4 < 8; ++i4) {
        float4 hv = hqa[i4];
        pa1 = fmaf(wh1[4 * i4 + 0], hv.x, pa1);
        pa1 = fmaf(wh1[4 * i4 + 1], hv.y, pa1);
        pa1 = fmaf(wh1[4 * i4 + 2], hv.z, pa1);
        pa1 = fmaf(wh1[4 * i4 + 3], hv.w, pa1);
      }
      #pragma unroll
      for (int i4 = 0; i4 < 8; ++i4) {
        float4 hv = hqb[i4];
        pa1 = fmaf(wx1[4 * i4 + 0], hv.x, pa1);
        pa1 = fmaf(wx1[4 * i4 + 1], hv.y, pa1);
        pa1 = fmaf(wx1[4 * i4 + 2], hv.z, pa1);
        pa1 = fmaf(wx1[4 * i4 + 3], hv.w, pa1);
        pt1 = fmaf(wt1[4 * i4 + 0], hv.x, pt1);
        pt1 = fmaf(wt1[4 * i4 + 1], hv.y, pt1);
        pt1 = fmaf(wt1[4 * i4 + 2], hv.z, pt1);
        pt1 = fmaf(wt1[4 * i4 + 3], hv.w, pt1);
      }
    }
    pA1[q * H_ + j] = pa1;
    pT1[q * H_ + j] = pt1;
    __syncthreads();                                             // B4

    float a1  = pA1[j] + pA1[H_ + j] + pA1[2 * H_ + j] + pA1[3 * H_ + j] + bhx1;
    float ta1 = pT1[j] + pT1[H_ + j] + pT1[2 * H_ + j] + pT1[3 * H_ + j] + bt1r;
    float f1   = tanh_fast(a1);
    float tu1  = tau1r + softplus_fast(ta1);
    float h1o  = hs1[j];
    float hc1  = fmaf(f1 - h1o, __builtin_amdgcn_rcpf(tu1), h1o);
    float u = hc1, u2 = hc1 * hc1;
    #pragma unroll
    for (int off = 32; off >= 1; off >>= 1) {
      u  += __shfl_xor(u, off);
      u2 += __shfl_xor(u2, off);
    }
    if (lane == 0) wsum1[wid] = make_float2(u, u2);
    __syncthreads();                                             // B5
    {
      float2 tA = wsum1[0], tB = wsum1[1];
      float mu1   = (tA.x + tB.x) * (1.f / 128.f);
      float var1  = (tA.y + tB.y) * (1.f / 128.f) - mu1 * mu1;
      float rstd1 = rsqrtf(var1 + EPS_);
      float hn1   = (hc1 - mu1) * rstd1 * g1r + be1r;
      if (q == 0) hs1[j] = hn1;
      out_hn1 = hn1;
    }

    // ---- x chunk rotation (reads of current chunk finished before B1) ----
    if ((t & (CH_ - 1)) == (CH_ - 1) && t != (T_ - 1)) {
      __syncthreads();
      xcu[tid] = r0; xcu[tid + 512] = r1;
      int c = (t >> 6) + 2;                       // next chunk to prefetch
      if (c < T_ / CH_) {
        r0 = xsrc[c * 1024 + tid];
        r1 = xsrc[c * 1024 + 512 + tid];
      }
      __syncthreads();
    }
  }

  if (q == 0) out[b * H_ + j] = out_hn1;
}

extern "C" void kernel_launch(void* const* d_in, const int* in_sizes, int n_in,
                              void* d_out, int out_size, void* d_ws, size_t ws_size,
                              hipStream_t stream) {
  const float* x    = (const float*)d_in[0];
  const float* Wh0  = (const float*)d_in[1];
  const float* bh0  = (const float*)d_in[2];
  const float* Wx0  = (const float*)d_in[3];
  const float* bx0  = (const float*)d_in[4];
  const float* Wt0  = (const float*)d_in[5];
  const float* bt0  = (const float*)d_in[6];
  const float* tau0 = (const float*)d_in[7];
  const float* g0   = (const float*)d_in[8];
  const float* be0  = (const float*)d_in[9];
  const float* Wh1  = (const float*)d_in[10];
  const float* bh1  = (const float*)d_in[11];
  const float* Wx1  = (const float*)d_in[12];
  const float* bx1  = (const float*)d_in[13];
  const float* Wt1  = (const float*)d_in[14];
  const float* bt1  = (const float*)d_in[15];
  const float* tau1 = (const float*)d_in[16];
  const float* g1   = (const float*)d_in[17];
  const float* be1  = (const float*)d_in[18];
  float* out        = (float*)d_out;

  ltc_scan<<<B_, NT_, 0, stream>>>(x, Wh0, bh0, Wx0, bx0, Wt0, bt0, tau0, g0, be0,
                                   Wh1, bh1, Wx1, bx1, Wt1, bt1, tau1, g1, be1, out);
}

// Round 3
// 1356.733 us; speedup vs baseline: 1.5652x; 1.5652x over previous
//
#include <hip/hip_runtime.h>
#include <stdint.h>

// LTC encoder B=256,T=1024,F=64,H=128, f32. One WG per batch row.
// Wave-specialized pipeline: waves 0-3 (A) = layer 0 at step t,
// waves 4-7 (B) = layer 1 at step t-1. 2 barriers per pipelined step.
// K-split 4 within a quad of lanes (DPP combine); 2 outputs per thread.

#define B_ 256
#define T_ 1024
#define F_ 64
#define H_ 128
#define EPS_ 1e-5f
#define NT_ 512

__device__ __forceinline__ float tanh_fast(float a) {
  float aa = fabsf(a);
  float e  = __expf(2.f * aa);          // inf for large -> th -> 1
  float th = 1.f - 2.f / (e + 1.f);
  return copysignf(th, a);
}
__device__ __forceinline__ float softplus_fast(float x) {
  return (x > 20.f) ? x : __logf(1.f + __expf(x));
}
// swizzle: +8 words per 32-word quarter -> quarter q starts at bank 8q
__device__ __forceinline__ int swz(int m) { return m + ((m >> 5) << 3); }

// shared tail: quad combine (DPP), cell math, LN (wave butterfly + LDS partials),
// state write. Exactly 2 __syncthreads.
__device__ __forceinline__ float ln_tail(
    float pa0, float pt0, float pa1, float pt1, float hold,
    float bhx, float btr, float taub, float gr, float ber,
    int par, int l, int wid, float2* part, int pbase,
    float* dst, int jp, bool we)
{
  pa0 += __shfl_xor(pa0, 1); pa0 += __shfl_xor(pa0, 2);
  pt0 += __shfl_xor(pt0, 1); pt0 += __shfl_xor(pt0, 2);
  pa1 += __shfl_xor(pa1, 1); pa1 += __shfl_xor(pa1, 2);
  pt1 += __shfl_xor(pt1, 1); pt1 += __shfl_xor(pt1, 2);
  float aa = par ? pa1 : pa0;       // parity split: one j' per lane
  float tt = par ? pt1 : pt0;
  float f   = tanh_fast(aa + bhx);
  float tau = taub + softplus_fast(tt + btr);
  float hc  = fmaf(f - hold, __builtin_amdgcn_rcpf(tau), hold);
  float s = hc, s2 = hc * hc;
  #pragma unroll
  for (int off = 1; off <= 32; off <<= 1) {
    s  += __shfl_xor(s, off);
    s2 += __shfl_xor(s2, off);
  }
  if (l == 0) part[wid] = make_float2(s, s2);
  __syncthreads();                                   // barrier 1
  float4 p01 = *(const float4*)(part + pbase);
  float4 p23 = *(const float4*)(part + pbase + 2);
  float mu = (p01.x + p01.z + p23.x + p23.z) * (1.f / 256.f);  // each j counted 2x
  float m2 = (p01.y + p01.w + p23.y + p23.w) * (1.f / 256.f);
  float rstd = rsqrtf(m2 - mu * mu + EPS_);
  float hn = fmaf((hc - mu) * rstd, gr, ber);
  if (we && (l & 2) == 0) dst[swz(jp)] = hn;
  __syncthreads();                                   // barrier 2
  return hn;
}

__global__ void __launch_bounds__(NT_, 2) ltc_scan(
    const float* __restrict__ x,
    const float* __restrict__ Wh0, const float* __restrict__ bh0,
    const float* __restrict__ Wx0, const float* __restrict__ bx0,
    const float* __restrict__ Wt0, const float* __restrict__ bt0,
    const float* __restrict__ tau0, const float* __restrict__ g0,
    const float* __restrict__ be0,
    const float* __restrict__ Wh1, const float* __restrict__ bh1,
    const float* __restrict__ Wx1, const float* __restrict__ bx1,
    const float* __restrict__ Wt1, const float* __restrict__ bt1,
    const float* __restrict__ tau1, const float* __restrict__ g1,
    const float* __restrict__ be1,
    float* __restrict__ out)
{
  __shared__ __align__(16) float  h0buf[2][160];   // swizzled H=128
  __shared__ __align__(16) float  h1buf[160];
  __shared__ __align__(16) float2 part[8];

  const int tid = threadIdx.x;
  const int wid = tid >> 6;
  const int l   = tid & 63;
  const int gw  = wid & 3;         // wave within group
  const int q   = l & 3;           // K-quarter
  const int k   = l >> 2;          // 0..15
  const int par = l & 1;
  const int j0  = gw * 16 + k;     // outputs j0 and j0+64
  const int jp  = j0 + (par ? 64 : 0);
  const int b   = blockIdx.x;

  if (tid < 160) { h0buf[0][tid] = 0.f; h0buf[1][tid] = 0.f; h1buf[tid] = 0.f; }
  __syncthreads();

  if (wid < 4) {
    // ================= group A: layer 0, step t = i =================
    float wh[64], wx[32], wt[32];
    {
      const float4* p0 = (const float4*)(Wh0 + j0 * H_ + q * 32);
      const float4* p1 = (const float4*)(Wh0 + (j0 + 64) * H_ + q * 32);
      #pragma unroll
      for (int i = 0; i < 8; ++i) { ((float4*)wh)[i] = p0[i]; ((float4*)wh)[8 + i] = p1[i]; }
      const float4* q0 = (const float4*)(Wx0 + j0 * F_ + q * 16);
      const float4* q1 = (const float4*)(Wx0 + (j0 + 64) * F_ + q * 16);
      #pragma unroll
      for (int i = 0; i < 4; ++i) { ((float4*)wx)[i] = q0[i]; ((float4*)wx)[4 + i] = q1[i]; }
      const float4* r0 = (const float4*)(Wt0 + j0 * F_ + q * 16);
      const float4* r1 = (const float4*)(Wt0 + (j0 + 64) * F_ + q * 16);
      #pragma unroll
      for (int i = 0; i < 4; ++i) { ((float4*)wt)[i] = r0[i]; ((float4*)wt)[4 + i] = r1[i]; }
    }
    const float bhx = bh0[jp] + bx0[jp];
    const float btr = bt0[jp];
    const float taub = tau0[jp];
    const float gr = g0[jp], ber = be0[jp];

    const float4* xg = (const float4*)(x + (size_t)b * (T_ * F_));
    // distance-2 register prefetch of the thread's x quarter (16 floats)
    float4 xa0 = xg[q * 4 + 0], xa1 = xg[q * 4 + 1], xa2 = xg[q * 4 + 2], xa3 = xg[q * 4 + 3];
    float4 xb0 = xg[16 + q * 4 + 0], xb1 = xg[16 + q * 4 + 1],
           xb2 = xg[16 + q * 4 + 2], xb3 = xg[16 + q * 4 + 3];

#define XFMA(xv, base)                                                     \
    pa0 = fmaf(wx[(base) + 0], (xv).x, pa0); pa0 = fmaf(wx[(base) + 1], (xv).y, pa0); \
    pa0 = fmaf(wx[(base) + 2], (xv).z, pa0); pa0 = fmaf(wx[(base) + 3], (xv).w, pa0); \
    pa1 = fmaf(wx[16 + (base) + 0], (xv).x, pa1); pa1 = fmaf(wx[16 + (base) + 1], (xv).y, pa1); \
    pa1 = fmaf(wx[16 + (base) + 2], (xv).z, pa1); pa1 = fmaf(wx[16 + (base) + 3], (xv).w, pa1); \
    pt0 = fmaf(wt[(base) + 0], (xv).x, pt0); pt0 = fmaf(wt[(base) + 1], (xv).y, pt0); \
    pt0 = fmaf(wt[(base) + 2], (xv).z, pt0); pt0 = fmaf(wt[(base) + 3], (xv).w, pt0); \
    pt1 = fmaf(wt[16 + (base) + 0], (xv).x, pt1); pt1 = fmaf(wt[16 + (base) + 1], (xv).y, pt1); \
    pt1 = fmaf(wt[16 + (base) + 2], (xv).z, pt1); pt1 = fmaf(wt[16 + (base) + 3], (xv).w, pt1);

    auto stepA = [&](int i, float4& x0, float4& x1, float4& x2, float4& x3) {
      const float* hp = h0buf[i & 1];                // h0[i-1]
      float pa0 = 0.f, pt0 = 0.f, pa1 = 0.f, pt1 = 0.f;
      #pragma unroll
      for (int ii = 0; ii < 8; ++ii) {
        float4 hv = *(const float4*)(hp + 40 * q + 4 * ii);
        pa0 = fmaf(wh[4 * ii + 0], hv.x, pa0); pa0 = fmaf(wh[4 * ii + 1], hv.y, pa0);
        pa0 = fmaf(wh[4 * ii + 2], hv.z, pa0); pa0 = fmaf(wh[4 * ii + 3], hv.w, pa0);
        pa1 = fmaf(wh[32 + 4 * ii + 0], hv.x, pa1); pa1 = fmaf(wh[32 + 4 * ii + 1], hv.y, pa1);
        pa1 = fmaf(wh[32 + 4 * ii + 2], hv.z, pa1); pa1 = fmaf(wh[32 + 4 * ii + 3], hv.w, pa1);
      }
      XFMA(x0, 0) XFMA(x1, 4) XFMA(x2, 8) XFMA(x3, 12)
      float hold = hp[swz(jp)];
      int tn = i + 2; if (tn > T_ - 1) tn = T_ - 1;   // reload this buffer for t=i+2
      const float4* xp = xg + tn * 16 + q * 4;
      x0 = xp[0]; x1 = xp[1]; x2 = xp[2]; x3 = xp[3];
      ln_tail(pa0, pt0, pa1, pt1, hold, bhx, btr, taub, gr, ber,
              par, l, wid, part, 0, h0buf[(i + 1) & 1], jp, true);
    };

    for (int i = 0; i < T_; i += 2) {
      stepA(i, xa0, xa1, xa2, xa3);
      stepA(i + 1, xb0, xb1, xb2, xb3);
    }
    stepA(T_, xa0, xa1, xa2, xa3);                   // pipeline drain (result unused)
#undef XFMA
  } else {
    // ================= group B: layer 1, step t = i-1 =================
    float wh[64], wx[64], wt[64];
    {
      const float4* p0 = (const float4*)(Wh1 + j0 * H_ + q * 32);
      const float4* p1 = (const float4*)(Wh1 + (j0 + 64) * H_ + q * 32);
      #pragma unroll
      for (int i = 0; i < 8; ++i) { ((float4*)wh)[i] = p0[i]; ((float4*)wh)[8 + i] = p1[i]; }
      const float4* q0 = (const float4*)(Wx1 + j0 * H_ + q * 32);
      const float4* q1 = (const float4*)(Wx1 + (j0 + 64) * H_ + q * 32);
      #pragma unroll
      for (int i = 0; i < 8; ++i) { ((float4*)wx)[i] = q0[i]; ((float4*)wx)[8 + i] = q1[i]; }
      const float4* r0 = (const float4*)(Wt1 + j0 * H_ + q * 32);
      const float4* r1 = (const float4*)(Wt1 + (j0 + 64) * H_ + q * 32);
      #pragma unroll
      for (int i = 0; i < 8; ++i) { ((float4*)wt)[i] = r0[i]; ((float4*)wt)[8 + i] = r1[i]; }
    }
    const float bhx = bh1[jp] + bx1[jp];
    const float btr = bt1[jp];
    const float taub = tau1[jp];
    const float gr = g1[jp], ber = be1[jp];

    float hnlast = 0.f;
    for (int i = 0; i <= T_; ++i) {
      const float* hp = h0buf[i & 1];                // h0[i-1] (layer-0 output)
      float pa0 = 0.f, pt0 = 0.f, pa1 = 0.f, pt1 = 0.f;
      #pragma unroll
      for (int ii = 0; ii < 8; ++ii) {               // Wh1 . h1[i-2]
        float4 hv = *(const float4*)(h1buf + 40 * q + 4 * ii);
        pa0 = fmaf(wh[4 * ii + 0], hv.x, pa0); pa0 = fmaf(wh[4 * ii + 1], hv.y, pa0);
        pa0 = fmaf(wh[4 * ii + 2], hv.z, pa0); pa0 = fmaf(wh[4 * ii + 3], hv.w, pa0);
        pa1 = fmaf(wh[32 + 4 * ii + 0], hv.x, pa1); pa1 = fmaf(wh[32 + 4 * ii + 1], hv.y, pa1);
        pa1 = fmaf(wh[32 + 4 * ii + 2], hv.z, pa1); pa1 = fmaf(wh[32 + 4 * ii + 3], hv.w, pa1);
      }
      #pragma unroll
      for (int ii = 0; ii < 8; ++ii) {               // Wx1/Wt1 . h0[i-1]
        float4 hv = *(const float4*)(hp + 40 * q + 4 * ii);
        pa0 = fmaf(wx[4 * ii + 0], hv.x, pa0); pa0 = fmaf(wx[4 * ii + 1], hv.y, pa0);
        pa0 = fmaf(wx[4 * ii + 2], hv.z, pa0); pa0 = fmaf(wx[4 * ii + 3], hv.w, pa0);
        pa1 = fmaf(wx[32 + 4 * ii + 0], hv.x, pa1); pa1 = fmaf(wx[32 + 4 * ii + 1], hv.y, pa1);
        pa1 = fmaf(wx[32 + 4 * ii + 2], hv.z, pa1); pa1 = fmaf(wx[32 + 4 * ii + 3], hv.w, pa1);
        pt0 = fmaf(wt[4 * ii + 0], hv.x, pt0); pt0 = fmaf(wt[4 * ii + 1], hv.y, pt0);
        pt0 = fmaf(wt[4 * ii + 2], hv.z, pt0); pt0 = fmaf(wt[4 * ii + 3], hv.w, pt0);
        pt1 = fmaf(wt[32 + 4 * ii + 0], hv.x, pt1); pt1 = fmaf(wt[32 + 4 * ii + 1], hv.y, pt1);
        pt1 = fmaf(wt[32 + 4 * ii + 2], hv.z, pt1); pt1 = fmaf(wt[32 + 4 * ii + 3], hv.w, pt1);
      }
      float hold = h1buf[swz(jp)];
      float hn = ln_tail(pa0, pt0, pa1, pt1, hold, bhx, btr, taub, gr, ber,
                         par, l, wid, part, 4, h1buf, jp, i > 0);
      if (i > 0) hnlast = hn;
    }
    if ((l & 2) == 0) out[b * H_ + jp] = hnlast;     // h1[T-1]
  }
}

extern "C" void kernel_launch(void* const* d_in, const int* in_sizes, int n_in,
                              void* d_out, int out_size, void* d_ws, size_t ws_size,
                              hipStream_t stream) {
  const float* x    = (const float*)d_in[0];
  const float* Wh0  = (const float*)d_in[1];
  const float* bh0  = (const float*)d_in[2];
  const float* Wx0  = (const float*)d_in[3];
  const float* bx0  = (const float*)d_in[4];
  const float* Wt0  = (const float*)d_in[5];
  const float* bt0  = (const float*)d_in[6];
  const float* tau0 = (const float*)d_in[7];
  const float* g0   = (const float*)d_in[8];
  const float* be0  = (const float*)d_in[9];
  const float* Wh1  = (const float*)d_in[10];
  const float* bh1  = (const float*)d_in[11];
  const float* Wx1  = (const float*)d_in[12];
  const float* bx1  = (const float*)d_in[13];
  const float* Wt1  = (const float*)d_in[14];
  const float* bt1  = (const float*)d_in[15];
  const float* tau1 = (const float*)d_in[16];
  const float* g1   = (const float*)d_in[17];
  const float* be1  = (const float*)d_in[18];
  float* out        = (float*)d_out;

  ltc_scan<<<B_, NT_, 0, stream>>>(x, Wh0, bh0, Wx0, bx0, Wt0, bt0, tau0, g0, be0,
                                   Wh1, bh1, Wx1, bx1, Wt1, bt1, tau1, g1, be1, out);
}

// Round 4
// 1346.590 us; speedup vs baseline: 1.5770x; 1.0075x over previous
//
#include <hip/hip_runtime.h>
#include <stdint.h>

// LTC encoder B=256,T=1024,F=64,H=128, f32. One WG per batch row.
// Wave-specialized pipeline: waves 0-3 (A) = layer 0 at step t,
// waves 4-7 (B) = layer 1 at step t-1. 2 barriers per pipelined step.
// K-split 4 within a quad of lanes (DPP combine); 2 outputs per thread.
// amdgpu_waves_per_eu(2,2): grid==CU count -> 1 block/CU; pin the register
// budget to 256 VGPR/wave so the 128-192 weight floats/thread stay
// register-resident (R3: compiler targeted 4 waves/EU, VGPR=116, and sank
// weight loads into the loop -> L2-BW-bound at 320 KB/CU/iter).

#define B_ 256
#define T_ 1024
#define F_ 64
#define H_ 128
#define EPS_ 1e-5f
#define NT_ 512

__device__ __forceinline__ float tanh_fast(float a) {
  float aa = fabsf(a);
  float e  = __expf(2.f * aa);          // inf for large -> th -> 1
  float th = 1.f - 2.f / (e + 1.f);
  return copysignf(th, a);
}
__device__ __forceinline__ float softplus_fast(float x) {
  return (x > 20.f) ? x : __logf(1.f + __expf(x));
}
// swizzle: +8 words per 32-word quarter -> quarter q starts at bank 8q
__device__ __forceinline__ int swz(int m) { return m + ((m >> 5) << 3); }

// shared tail: quad combine (DPP), cell math, LN (wave butterfly + LDS partials),
// state write. Exactly 2 __syncthreads.
__device__ __forceinline__ float ln_tail(
    float pa0, float pt0, float pa1, float pt1, float hold,
    float bhx, float btr, float taub, float gr, float ber,
    int par, int l, int wid, float2* part, int pbase,
    float* dst, int jp, bool we)
{
  pa0 += __shfl_xor(pa0, 1); pa0 += __shfl_xor(pa0, 2);
  pt0 += __shfl_xor(pt0, 1); pt0 += __shfl_xor(pt0, 2);
  pa1 += __shfl_xor(pa1, 1); pa1 += __shfl_xor(pa1, 2);
  pt1 += __shfl_xor(pt1, 1); pt1 += __shfl_xor(pt1, 2);
  float aa = par ? pa1 : pa0;       // parity split: one j' per lane
  float tt = par ? pt1 : pt0;
  float f   = tanh_fast(aa + bhx);
  float tau = taub + softplus_fast(tt + btr);
  float hc  = fmaf(f - hold, __builtin_amdgcn_rcpf(tau), hold);
  float s = hc, s2 = hc * hc;
  #pragma unroll
  for (int off = 1; off <= 32; off <<= 1) {
    s  += __shfl_xor(s, off);
    s2 += __shfl_xor(s2, off);
  }
  if (l == 0) part[wid] = make_float2(s, s2);
  __syncthreads();                                   // barrier 1
  float4 p01 = *(const float4*)(part + pbase);
  float4 p23 = *(const float4*)(part + pbase + 2);
  float mu = (p01.x + p01.z + p23.x + p23.z) * (1.f / 256.f);  // each j counted 2x
  float m2 = (p01.y + p01.w + p23.y + p23.w) * (1.f / 256.f);
  float rstd = rsqrtf(m2 - mu * mu + EPS_);
  float hn = fmaf((hc - mu) * rstd, gr, ber);
  if (we && (l & 2) == 0) dst[swz(jp)] = hn;
  __syncthreads();                                   // barrier 2
  return hn;
}

__global__ void __attribute__((amdgpu_flat_work_group_size(NT_, NT_)))
                __attribute__((amdgpu_waves_per_eu(2, 2)))
ltc_scan(
    const float* __restrict__ x,
    const float* __restrict__ Wh0, const float* __restrict__ bh0,
    const float* __restrict__ Wx0, const float* __restrict__ bx0,
    const float* __restrict__ Wt0, const float* __restrict__ bt0,
    const float* __restrict__ tau0, const float* __restrict__ g0,
    const float* __restrict__ be0,
    const float* __restrict__ Wh1, const float* __restrict__ bh1,
    const float* __restrict__ Wx1, const float* __restrict__ bx1,
    const float* __restrict__ Wt1, const float* __restrict__ bt1,
    const float* __restrict__ tau1, const float* __restrict__ g1,
    const float* __restrict__ be1,
    float* __restrict__ out)
{
  __shared__ __align__(16) float  h0buf[2][160];   // swizzled H=128
  __shared__ __align__(16) float  h1buf[160];
  __shared__ __align__(16) float2 part[8];

  const int tid = threadIdx.x;
  const int wid = tid >> 6;
  const int l   = tid & 63;
  const int gw  = wid & 3;         // wave within group
  const int q   = l & 3;           // K-quarter
  const int k   = l >> 2;          // 0..15
  const int par = l & 1;
  const int j0  = gw * 16 + k;     // outputs j0 and j0+64
  const int jp  = j0 + (par ? 64 : 0);
  const int b   = blockIdx.x;

  if (tid < 160) { h0buf[0][tid] = 0.f; h0buf[1][tid] = 0.f; h1buf[tid] = 0.f; }
  __syncthreads();

  if (wid < 4) {
    // ================= group A: layer 0, step t = i =================
    float wh[64], wx[32], wt[32];
    {
      const float4* p0 = (const float4*)(Wh0 + j0 * H_ + q * 32);
      const float4* p1 = (const float4*)(Wh0 + (j0 + 64) * H_ + q * 32);
      #pragma unroll
      for (int i = 0; i < 8; ++i) { ((float4*)wh)[i] = p0[i]; ((float4*)wh)[8 + i] = p1[i]; }
      const float4* q0 = (const float4*)(Wx0 + j0 * F_ + q * 16);
      const float4* q1 = (const float4*)(Wx0 + (j0 + 64) * F_ + q * 16);
      #pragma unroll
      for (int i = 0; i < 4; ++i) { ((float4*)wx)[i] = q0[i]; ((float4*)wx)[4 + i] = q1[i]; }
      const float4* r0 = (const float4*)(Wt0 + j0 * F_ + q * 16);
      const float4* r1 = (const float4*)(Wt0 + (j0 + 64) * F_ + q * 16);
      #pragma unroll
      for (int i = 0; i < 4; ++i) { ((float4*)wt)[i] = r0[i]; ((float4*)wt)[4 + i] = r1[i]; }
    }
    const float bhx = bh0[jp] + bx0[jp];
    const float btr = bt0[jp];
    const float taub = tau0[jp];
    const float gr = g0[jp], ber = be0[jp];

    const float4* xg = (const float4*)(x + (size_t)b * (T_ * F_));
    // distance-2 register prefetch of the thread's x quarter (16 floats)
    float4 xa0 = xg[q * 4 + 0], xa1 = xg[q * 4 + 1], xa2 = xg[q * 4 + 2], xa3 = xg[q * 4 + 3];
    float4 xb0 = xg[16 + q * 4 + 0], xb1 = xg[16 + q * 4 + 1],
           xb2 = xg[16 + q * 4 + 2], xb3 = xg[16 + q * 4 + 3];

#define XFMA(xv, base)                                                     \
    pa0 = fmaf(wx[(base) + 0], (xv).x, pa0); pa0 = fmaf(wx[(base) + 1], (xv).y, pa0); \
    pa0 = fmaf(wx[(base) + 2], (xv).z, pa0); pa0 = fmaf(wx[(base) + 3], (xv).w, pa0); \
    pa1 = fmaf(wx[16 + (base) + 0], (xv).x, pa1); pa1 = fmaf(wx[16 + (base) + 1], (xv).y, pa1); \
    pa1 = fmaf(wx[16 + (base) + 2], (xv).z, pa1); pa1 = fmaf(wx[16 + (base) + 3], (xv).w, pa1); \
    pt0 = fmaf(wt[(base) + 0], (xv).x, pt0); pt0 = fmaf(wt[(base) + 1], (xv).y, pt0); \
    pt0 = fmaf(wt[(base) + 2], (xv).z, pt0); pt0 = fmaf(wt[(base) + 3], (xv).w, pt0); \
    pt1 = fmaf(wt[16 + (base) + 0], (xv).x, pt1); pt1 = fmaf(wt[16 + (base) + 1], (xv).y, pt1); \
    pt1 = fmaf(wt[16 + (base) + 2], (xv).z, pt1); pt1 = fmaf(wt[16 + (base) + 3], (xv).w, pt1);

    auto stepA = [&](int i, float4& x0, float4& x1, float4& x2, float4& x3) {
      const float* hp = h0buf[i & 1];                // h0[i-1]
      float pa0 = 0.f, pt0 = 0.f, pa1 = 0.f, pt1 = 0.f;
      #pragma unroll
      for (int ii = 0; ii < 8; ++ii) {
        float4 hv = *(const float4*)(hp + 40 * q + 4 * ii);
        pa0 = fmaf(wh[4 * ii + 0], hv.x, pa0); pa0 = fmaf(wh[4 * ii + 1], hv.y, pa0);
        pa0 = fmaf(wh[4 * ii + 2], hv.z, pa0); pa0 = fmaf(wh[4 * ii + 3], hv.w, pa0);
        pa1 = fmaf(wh[32 + 4 * ii + 0], hv.x, pa1); pa1 = fmaf(wh[32 + 4 * ii + 1], hv.y, pa1);
        pa1 = fmaf(wh[32 + 4 * ii + 2], hv.z, pa1); pa1 = fmaf(wh[32 + 4 * ii + 3], hv.w, pa1);
      }
      XFMA(x0, 0) XFMA(x1, 4) XFMA(x2, 8) XFMA(x3, 12)
      float hold = hp[swz(jp)];
      int tn = i + 2; if (tn > T_ - 1) tn = T_ - 1;   // reload this buffer for t=i+2
      const float4* xp = xg + tn * 16 + q * 4;
      x0 = xp[0]; x1 = xp[1]; x2 = xp[2]; x3 = xp[3];
      ln_tail(pa0, pt0, pa1, pt1, hold, bhx, btr, taub, gr, ber,
              par, l, wid, part, 0, h0buf[(i + 1) & 1], jp, true);
    };

    for (int i = 0; i < T_; i += 2) {
      stepA(i, xa0, xa1, xa2, xa3);
      stepA(i + 1, xb0, xb1, xb2, xb3);
    }
    stepA(T_, xa0, xa1, xa2, xa3);                   // pipeline drain (result unused)
#undef XFMA
  } else {
    // ================= group B: layer 1, step t = i-1 =================
    float wh[64], wx[64], wt[64];
    {
      const float4* p0 = (const float4*)(Wh1 + j0 * H_ + q * 32);
      const float4* p1 = (const float4*)(Wh1 + (j0 + 64) * H_ + q * 32);
      #pragma unroll
      for (int i = 0; i < 8; ++i) { ((float4*)wh)[i] = p0[i]; ((float4*)wh)[8 + i] = p1[i]; }
      const float4* q0 = (const float4*)(Wx1 + j0 * H_ + q * 32);
      const float4* q1 = (const float4*)(Wx1 + (j0 + 64) * H_ + q * 32);
      #pragma unroll
      for (int i = 0; i < 8; ++i) { ((float4*)wx)[i] = q0[i]; ((float4*)wx)[8 + i] = q1[i]; }
      const float4* r0 = (const float4*)(Wt1 + j0 * H_ + q * 32);
      const float4* r1 = (const float4*)(Wt1 + (j0 + 64) * H_ + q * 32);
      #pragma unroll
      for (int i = 0; i < 8; ++i) { ((float4*)wt)[i] = r0[i]; ((float4*)wt)[8 + i] = r1[i]; }
    }
    const float bhx = bh1[jp] + bx1[jp];
    const float btr = bt1[jp];
    const float taub = tau1[jp];
    const float gr = g1[jp], ber = be1[jp];

    float hnlast = 0.f;
    for (int i = 0; i <= T_; ++i) {
      const float* hp = h0buf[i & 1];                // h0[i-1] (layer-0 output)
      float pa0 = 0.f, pt0 = 0.f, pa1 = 0.f, pt1 = 0.f;
      #pragma unroll
      for (int ii = 0; ii < 8; ++ii) {               // Wh1 . h1[i-2]
        float4 hv = *(const float4*)(h1buf + 40 * q + 4 * ii);
        pa0 = fmaf(wh[4 * ii + 0], hv.x, pa0); pa0 = fmaf(wh[4 * ii + 1], hv.y, pa0);
        pa0 = fmaf(wh[4 * ii + 2], hv.z, pa0); pa0 = fmaf(wh[4 * ii + 3], hv.w, pa0);
        pa1 = fmaf(wh[32 + 4 * ii + 0], hv.x, pa1); pa1 = fmaf(wh[32 + 4 * ii + 1], hv.y, pa1);
        pa1 = fmaf(wh[32 + 4 * ii + 2], hv.z, pa1); pa1 = fmaf(wh[32 + 4 * ii + 3], hv.w, pa1);
      }
      #pragma unroll
      for (int ii = 0; ii < 8; ++ii) {               // Wx1/Wt1 . h0[i-1]
        float4 hv = *(const float4*)(hp + 40 * q + 4 * ii);
        pa0 = fmaf(wx[4 * ii + 0], hv.x, pa0); pa0 = fmaf(wx[4 * ii + 1], hv.y, pa0);
        pa0 = fmaf(wx[4 * ii + 2], hv.z, pa0); pa0 = fmaf(wx[4 * ii + 3], hv.w, pa0);
        pa1 = fmaf(wx[32 + 4 * ii + 0], hv.x, pa1); pa1 = fmaf(wx[32 + 4 * ii + 1], hv.y, pa1);
        pa1 = fmaf(wx[32 + 4 * ii + 2], hv.z, pa1); pa1 = fmaf(wx[32 + 4 * ii + 3], hv.w, pa1);
        pt0 = fmaf(wt[4 * ii + 0], hv.x, pt0); pt0 = fmaf(wt[4 * ii + 1], hv.y, pt0);
        pt0 = fmaf(wt[4 * ii + 2], hv.z, pt0); pt0 = fmaf(wt[4 * ii + 3], hv.w, pt0);
        pt1 = fmaf(wt[32 + 4 * ii + 0], hv.x, pt1); pt1 = fmaf(wt[32 + 4 * ii + 1], hv.y, pt1);
        pt1 = fmaf(wt[32 + 4 * ii + 2], hv.z, pt1); pt1 = fmaf(wt[32 + 4 * ii + 3], hv.w, pt1);
      }
      float hold = h1buf[swz(jp)];
      float hn = ln_tail(pa0, pt0, pa1, pt1, hold, bhx, btr, taub, gr, ber,
                         par, l, wid, part, 4, h1buf, jp, i > 0);
      if (i > 0) hnlast = hn;
    }
    if ((l & 2) == 0) out[b * H_ + jp] = hnlast;     // h1[T-1]
  }
}

extern "C" void kernel_launch(void* const* d_in, const int* in_sizes, int n_in,
                              void* d_out, int out_size, void* d_ws, size_t ws_size,
                              hipStream_t stream) {
  const float* x    = (const float*)d_in[0];
  const float* Wh0  = (const float*)d_in[1];
  const float* bh0  = (const float*)d_in[2];
  const float* Wx0  = (const float*)d_in[3];
  const float* bx0  = (const float*)d_in[4];
  const float* Wt0  = (const float*)d_in[5];
  const float* bt0  = (const float*)d_in[6];
  const float* tau0 = (const float*)d_in[7];
  const float* g0   = (const float*)d_in[8];
  const float* be0  = (const float*)d_in[9];
  const float* Wh1  = (const float*)d_in[10];
  const float* bh1  = (const float*)d_in[11];
  const float* Wx1  = (const float*)d_in[12];
  const float* bx1  = (const float*)d_in[13];
  const float* Wt1  = (const float*)d_in[14];
  const float* bt1  = (const float*)d_in[15];
  const float* tau1 = (const float*)d_in[16];
  const float* g1   = (const float*)d_in[17];
  const float* be1  = (const float*)d_in[18];
  float* out        = (float*)d_out;

  ltc_scan<<<B_, NT_, 0, stream>>>(x, Wh0, bh0, Wx0, bx0, Wt0, bt0, tau0, g0, be0,
                                   Wh1, bh1, Wx1, bx1, Wt1, bt1, tau1, g1, be1, out);
}